// Round 1
// baseline (574.174 us; speedup 1.0000x reference)
//
#include <hip/hip_runtime.h>

// Problem constants
#define B_N 4096
#define T_N 512
// Output layout (floats): final (B,T,2) | fwd_out (B,2) | noise (B,T,1)
#define FWD_OFF   (B_N * T_N * 2)        // 4194304
#define NOISE_OFF (FWD_OFF + B_N * 2)    // 4202496

#define S_SIG  (-1.4426950408889634f)   // -log2(e)
#define S_TANH (-2.8853900817779268f)   // -2*log2(e)

typedef float v2f __attribute__((ext_vector_type(2)));

__device__ __forceinline__ v2f mkv2(float a, float b) { v2f r; r.x = a; r.y = b; return r; }

// packed fp32 fma: d = a*b + c elementwise (v_pk_fma_f32, full-rate on CDNA)
__device__ __forceinline__ v2f pk_fma(v2f a, v2f b, v2f c) {
    v2f d;
    asm("v_pk_fma_f32 %0, %1, %2, %3" : "=v"(d) : "v"(a), "v"(b), "v"(c));
    return d;
}

// act on pre-scaled accumulator: returns fma(A, rcp(1+exp2(a)), B)
// A=1,B=0  -> sigmoid(v) where a = -log2e*v
// A=2,B=-1 -> tanh(v)    where a = -2log2e*v
__device__ __forceinline__ float act_ab(float a, float A, float Bc) {
    float r = __builtin_amdgcn_rcpf(1.0f + __builtin_amdgcn_exp2f(a));
    return fmaf(A, r, Bc);
}
__device__ __forceinline__ float sig_acc(float a) {
    return __builtin_amdgcn_rcpf(1.0f + __builtin_amdgcn_exp2f(a));
}
__device__ __forceinline__ float tanh_nat(float v) {
    return fmaf(2.0f, __builtin_amdgcn_rcpf(1.0f + __builtin_amdgcn_exp2f(v * S_TANH)), -1.0f);
}

// 32 lanes per batch element (2 elements/wave) -> 2048 waves = 2 waves/SIMD.
// Encoder: lanes 0-15 = L0 gate rows, lanes 16-31 = L1 gate rows, layer-pipelined
//          (L1 runs one step behind L0; valid because encoder has no h1->L0 feedback).
// Decoder: gate-split: lanes 0-15 compute gates {i,f} of unit u=l&15,
//          lanes 16-31 compute gates {g,o}; combine via 2 width-32 shuffles.
__global__ __attribute__((amdgpu_waves_per_eu(2))) __launch_bounds__(256)
void fused_kernel(
    const float* __restrict__ x,
    const float* __restrict__ eWih0, const float* __restrict__ eWhh0,
    const float* __restrict__ ebih0, const float* __restrict__ ebhh0,
    const float* __restrict__ eWih1, const float* __restrict__ eWhh1,
    const float* __restrict__ ebih1, const float* __restrict__ ebhh1,
    const float* __restrict__ dWih0, const float* __restrict__ dWhh0,
    const float* __restrict__ dbih0, const float* __restrict__ dbhh0,
    const float* __restrict__ dWih1, const float* __restrict__ dWhh1,
    const float* __restrict__ dbih1, const float* __restrict__ dbhh1,
    const float* __restrict__ fcW, const float* __restrict__ fcb,
    const float* __restrict__ outW, const float* __restrict__ outb,
    float* __restrict__ out)
{
    const int tid = blockIdx.x * 256 + threadIdx.x;
    const int b   = tid >> 5;     // batch element
    const int l   = tid & 31;     // lane within element group (32)
    const int r16 = l & 15;       // row/unit lane within half
    const int gg  = l >> 4;       // 0 = first half, 1 = second half

    // =================== ENCODER: dual-layer pipelined (H=4) ===================
    // half gg==0: L0 gate rows r16; half gg==1: L1 gate rows r16.
    const int u4 = r16 & 3;
    const int kk = r16 >> 2;
    const float sc = (kk == 2) ? S_TANH : S_SIG;
    const float Ak = (kk == 2) ? 2.0f : 1.0f;
    const float Bk = (kk == 2) ? -1.0f : 0.0f;

    const float* whsrc = gg ? eWhh1 : eWhh0;
    const float wx    = gg ? 0.0f : eWih0[r16] * sc;                 // x weight (L0 only)
    const float ebias = ((gg ? ebih1[r16] : ebih0[r16]) +
                         (gg ? ebhh1[r16] : ebhh0[r16])) * sc;
    v2f whp0 = mkv2(whsrc[r16 * 4 + 0], whsrc[r16 * 4 + 1]) * sc;    // self-h weights
    v2f whp1 = mkv2(whsrc[r16 * 4 + 2], whsrc[r16 * 4 + 3]) * sc;
    v2f wip0 = gg ? mkv2(eWih1[r16 * 4 + 0], eWih1[r16 * 4 + 1]) * sc : mkv2(0.f, 0.f);
    v2f wip1 = gg ? mkv2(eWih1[r16 * 4 + 2], eWih1[r16 * 4 + 3]) * sc : mkv2(0.f, 0.f);

    // state: vp = own-layer h (L0: h0, L1: h1); wq = h0 from L0 half (width-32 bcast)
    v2f vp0 = mkv2(0.f, 0.f), vp1 = mkv2(0.f, 0.f);
    v2f wq0 = mkv2(0.f, 0.f), wq1 = mkv2(0.f, 0.f);
    float c = 0.f, hu = 0.f;

    auto ebody = [&](float xc) {
        v2f acc = pk_fma(whp0, vp0, mkv2(fmaf(wx, xc, ebias), 0.f));
        acc = pk_fma(whp1, vp1, acc);
        acc = pk_fma(wip0, wq0, acc);   // L1: Wih1 . h0(prev body); L0: zero
        acc = pk_fma(wip1, wq1, acc);
        float gate = act_ab(acc.x + acc.y, Ak, Bk);
        float fv = __shfl(gate, u4 + 4, 16);
        float gv = __shfl(gate, u4 + 8, 16);
        float ov = __shfl(gate, u4 + 12, 16);
        c = fmaf(fv, c, gate * gv);          // valid on r16 0..3 of each half
        hu = ov * tanh_nat(c);
        // own-layer h broadcast (within 16-lane half)
        vp0.x = __shfl(hu, 0, 16); vp0.y = __shfl(hu, 1, 16);
        vp1.x = __shfl(hu, 2, 16); vp1.y = __shfl(hu, 3, 16);
        // h0 broadcast to both halves (lanes 0..3 of the 32-group)
        wq0.x = __shfl(hu, 0, 32); wq0.y = __shfl(hu, 1, 32);
        wq1.x = __shfl(hu, 2, 32); wq1.y = __shfl(hu, 3, 32);
    };

    const float4* __restrict__ xq4 = (const float4*)(x + (long)b * T_N);
    float4 xq = xq4[0];
    float4 xn = xq4[1];

    ebody(xq.x);                                   // s=0: L0 computes h0(0); L1 ran bogus step
    if (gg) {                                      // neutralize L1's bogus first step
        c = 0.f; vp0 = mkv2(0.f, 0.f); vp1 = mkv2(0.f, 0.f);
    }
    ebody(xq.y); ebody(xq.z); ebody(xq.w);         // s=1..3
    xq = xn;
#pragma unroll 1
    for (int tb = 1; tb < T_N / 4; ++tb) {         // s=4..511
        xn = (tb + 1 < T_N / 4) ? xq4[tb + 1] : xq;
        ebody(xq.x); ebody(xq.y); ebody(xq.z); ebody(xq.w);
        xq = xn;
    }
    // After 512 bodies: L0 final h0(511) in wq*, c (lanes 0-3) = c0 final.
    // L1 is at h1(510): save L0 handoff, run one more body for h1(511).
    const v2f h0f0 = wq0, h0f1 = wq1;
    const float c0f = c;
    ebody(0.f);                                    // s=512: only L1 half meaningful
    // hu on lanes 16..19 = h1 final units; c on lanes 16..19 = c1 final.

    const float h1f0 = __shfl(hu, 16, 32);
    const float h1f1 = __shfl(hu, 17, 32);
    const float h1f2 = __shfl(hu, 18, 32);
    const float h1f3 = __shfl(hu, 19, 32);

    // fwd_out = h1 @ fc_W.T + fc_b (uniform on all lanes)
    float fw0 = fcb[0], fw1 = fcb[1];
    fw0 = fmaf(fcW[0], h1f0, fw0); fw0 = fmaf(fcW[1], h1f1, fw0);
    fw0 = fmaf(fcW[2], h1f2, fw0); fw0 = fmaf(fcW[3], h1f3, fw0);
    fw1 = fmaf(fcW[4], h1f0, fw1); fw1 = fmaf(fcW[5], h1f1, fw1);
    fw1 = fmaf(fcW[6], h1f2, fw1); fw1 = fmaf(fcW[7], h1f3, fw1);
    if (l == 0) {
        out[FWD_OFF + b * 2 + 0] = fw0;
        out[FWD_OFF + b * 2 + 1] = fw1;
    }

    __builtin_amdgcn_sched_barrier(0);  // keep decoder weight loads out of the encoder

    // =================== DECODER: gate-split (H=10) ===================
    // lane (gg,u): gg==0 computes gates {i(0), f(1)} of unit u; gg==1 computes {g(2), o(3)}.
    // Lanes with u in 10..15 shadow unit 9 (never read).
    const int u  = r16;
    const int uc = (u < 10) ? u : 9;
    const int r0 = (gg * 2 + 0) * 10 + uc;         // gate row for slot a (i or g)
    const int r1 = (gg * 2 + 1) * 10 + uc;         // gate row for slot b (f or o)
    const float sc0 = gg ? S_TANH : S_SIG;         // slot a: tanh iff it's the g-gate
    const float A0v = gg ? 2.0f : 1.0f;
    const float B0v = gg ? -1.0f : 0.0f;

    const float wih0a = dWih0[r0] * sc0;
    const float wih0b = dWih0[r1] * S_SIG;
    const float b0a = (dbih0[r0] + dbhh0[r0]) * sc0;
    const float b0b = (dbih0[r1] + dbhh0[r1]) * S_SIG;
    const float b1a = (dbih1[r0] + dbhh1[r0]) * sc0;
    const float b1b = (dbih1[r1] + dbhh1[r1]) * S_SIG;

    v2f whh0a[5], whh0b[5], wih1a[5], wih1b[5], whh1a[5], whh1b[5];
#pragma unroll
    for (int j = 0; j < 5; ++j) {
        whh0a[j] = mkv2(dWhh0[r0 * 10 + 2 * j], dWhh0[r0 * 10 + 2 * j + 1]) * sc0;
        whh0b[j] = mkv2(dWhh0[r1 * 10 + 2 * j], dWhh0[r1 * 10 + 2 * j + 1]) * S_SIG;
        wih1a[j] = mkv2(dWih1[r0 * 10 + 2 * j], dWih1[r0 * 10 + 2 * j + 1]) * sc0;
        wih1b[j] = mkv2(dWih1[r1 * 10 + 2 * j], dWih1[r1 * 10 + 2 * j + 1]) * S_SIG;
        whh1a[j] = mkv2(dWhh1[r0 * 10 + 2 * j], dWhh1[r0 * 10 + 2 * j + 1]) * sc0;
        whh1b[j] = mkv2(dWhh1[r1 * 10 + 2 * j], dWhh1[r1 * 10 + 2 * j + 1]) * S_SIG;
    }
    v2f outwp[5];
#pragma unroll
    for (int j = 0; j < 5; ++j) outwp[j] = mkv2(outW[2 * j], outW[2 * j + 1]);
    const float outb0 = outb[0];

    // Initial decoder state: encoder finals padded 4 -> 10 with zeros
    v2f dh0p[5], dh1p[5];
    dh0p[0] = h0f0; dh0p[1] = h0f1;
    dh1p[0] = mkv2(h1f0, h1f1); dh1p[1] = mkv2(h1f2, h1f3);
#pragma unroll
    for (int j = 2; j < 5; ++j) { dh0p[j] = mkv2(0.f, 0.f); dh1p[j] = mkv2(0.f, 0.f); }
    float dc0 = (u < 4) ? __shfl(c0f, u, 32) : 0.f;        // c0 lives on lanes 0..3
    float dc1 = (u < 4) ? __shfl(c, u + 16, 32) : 0.f;     // c1 lives on lanes 16..19

    float my_noise = 0.f;

#pragma unroll 1
    for (int t = 0; t < T_N; ++t) {
        // L1 partial from previous h1 (independent of L0 chain)
        v2f p1a = pk_fma(whh1a[0], dh1p[0], mkv2(b1a, 0.f));
        v2f p1b = pk_fma(whh1b[0], dh1p[0], mkv2(b1b, 0.f));
#pragma unroll
        for (int j = 1; j < 5; ++j) {
            p1a = pk_fma(whh1a[j], dh1p[j], p1a);
            p1b = pk_fma(whh1b[j], dh1p[j], p1b);
        }
        const float inp = dh1p[0].x;   // h1[0], uniform on all lanes

        // L0 gates (2 per lane)
        v2f ga = pk_fma(whh0a[0], dh0p[0], mkv2(fmaf(wih0a, inp, b0a), 0.f));
        v2f gb = pk_fma(whh0b[0], dh0p[0], mkv2(fmaf(wih0b, inp, b0b), 0.f));
#pragma unroll
        for (int j = 1; j < 5; ++j) {
            ga = pk_fma(whh0a[j], dh0p[j], ga);
            gb = pk_fma(whh0b[j], dh0p[j], gb);
        }
        float a0 = act_ab(ga.x + ga.y, A0v, B0v);  // half0: sig(i), half1: tanh(g)
        float a1 = sig_acc(gb.x + gb.y);           // half0: sig(f), half1: sig(o)
        float gv = __shfl(a0, u + 16, 32);         // tanh(g) from other half
        float ov = __shfl(a1, u + 16, 32);         // sig(o) from other half
        dc0 = fmaf(a1, dc0, a0 * gv);              // valid on half0, u<10
        const float h0u = ov * tanh_nat(dc0);
#pragma unroll
        for (int j = 0; j < 5; ++j) {
            dh0p[j].x = __shfl(h0u, 2 * j, 32);
            dh0p[j].y = __shfl(h0u, 2 * j + 1, 32);
        }

        // L1 gates: accumulate the post-broadcast half into p1
#pragma unroll
        for (int j = 0; j < 5; ++j) {
            p1a = pk_fma(wih1a[j], dh0p[j], p1a);
            p1b = pk_fma(wih1b[j], dh0p[j], p1b);
        }
        a0 = act_ab(p1a.x + p1a.y, A0v, B0v);
        a1 = sig_acc(p1b.x + p1b.y);
        gv = __shfl(a0, u + 16, 32);
        ov = __shfl(a1, u + 16, 32);
        dc1 = fmaf(a1, dc1, a0 * gv);
        const float h1u = ov * tanh_nat(dc1);
#pragma unroll
        for (int j = 0; j < 5; ++j) {
            dh1p[j].x = __shfl(h1u, 2 * j, 32);
            dh1p[j].y = __shfl(h1u, 2 * j + 1, 32);
        }

        // noise_t = dec_out . out_W + out_b (uniform on all lanes)
        v2f na = pk_fma(outwp[0], dh1p[0], mkv2(outb0, 0.f));
#pragma unroll
        for (int j = 1; j < 5; ++j) na = pk_fma(outwp[j], dh1p[j], na);
        const float nz = na.x + na.y;

        // lane u keeps t with t%16==u; flush coalesced every 16 steps (half0 only)
        my_noise = ((t & 15) == u) ? nz : my_noise;
        if ((t & 15) == 15 && l < 16) {
            const int idx = b * T_N + (t - 15) + u;
            out[NOISE_OFF + idx] = my_noise;
            float2 fin;
            fin.x = my_noise + fw0;
            fin.y = my_noise + fw1;
            ((float2*)out)[idx] = fin;
        }
    }
}

extern "C" void kernel_launch(void* const* d_in, const int* in_sizes, int n_in,
                              void* d_out, int out_size, void* d_ws, size_t ws_size,
                              hipStream_t stream) {
    const float* x     = (const float*)d_in[0];
    // d_in[1] = context (unused by the reference)
    const float* eWih0 = (const float*)d_in[2];
    const float* eWhh0 = (const float*)d_in[3];
    const float* ebih0 = (const float*)d_in[4];
    const float* ebhh0 = (const float*)d_in[5];
    const float* eWih1 = (const float*)d_in[6];
    const float* eWhh1 = (const float*)d_in[7];
    const float* ebih1 = (const float*)d_in[8];
    const float* ebhh1 = (const float*)d_in[9];
    const float* dWih0 = (const float*)d_in[10];
    const float* dWhh0 = (const float*)d_in[11];
    const float* dbih0 = (const float*)d_in[12];
    const float* dbhh0 = (const float*)d_in[13];
    const float* dWih1 = (const float*)d_in[14];
    const float* dWhh1 = (const float*)d_in[15];
    const float* dbih1 = (const float*)d_in[16];
    const float* dbhh1 = (const float*)d_in[17];
    const float* fcW   = (const float*)d_in[18];
    const float* fcb   = (const float*)d_in[19];
    const float* outW  = (const float*)d_in[20];
    const float* outb  = (const float*)d_in[21];

    float* out = (float*)d_out;

    // 4096 elems x 32 lanes = 131072 threads = 2048 waves = 2 waves/SIMD
    fused_kernel<<<dim3((B_N * 32) / 256), dim3(256), 0, stream>>>(
        x, eWih0, eWhh0, ebih0, ebhh0, eWih1, eWhh1, ebih1, ebhh1,
        dWih0, dWhh0, dbih0, dbhh0, dWih1, dWhh1, dbih1, dbhh1,
        fcW, fcb, outW, outb, out);
}